// Round 12
// baseline (618.032 us; speedup 1.0000x reference)
//
#include <hip/hip_runtime.h>
#include <hip/hip_bf16.h>

#define D 128
#define DV 32   // float4 per row

typedef float4 f4;
typedef unsigned short ushort_t;
typedef unsigned int uint_t;
typedef __attribute__((ext_vector_type(8))) short short8;
typedef __attribute__((ext_vector_type(8))) unsigned short ushort8;
typedef __attribute__((ext_vector_type(4))) float f32x4;
typedef __attribute__((ext_vector_type(2))) float f32x2;

__device__ __forceinline__ void f4add(f4& a, const f4& b) {
    a.x += b.x; a.y += b.y; a.z += b.z; a.w += b.w;
}
__device__ __forceinline__ float b2f(ushort_t u) {
    union { unsigned int i; float f; } v; v.i = ((unsigned int)u) << 16; return v.f;
}
__device__ __forceinline__ ushort_t f2b(float f) {
    __hip_bfloat16 b = __float2bfloat16(f);
    return *reinterpret_cast<ushort_t*>(&b);
}
// fp8 e4m3 (OCP on gfx950) hw converts
__device__ __forceinline__ f4 fp8x4_to_f4(uint_t v) {
    f32x2 lo = __builtin_amdgcn_cvt_pk_f32_fp8((int)v, false);
    f32x2 hi = __builtin_amdgcn_cvt_pk_f32_fp8((int)v, true);
    return make_float4(lo[0], lo[1], hi[0], hi[1]);
}
__device__ __forceinline__ uint_t f4_to_fp8x4(f4 v) {
    int r = 0;
    r = __builtin_amdgcn_cvt_pk_fp8_f32(v.x, v.y, r, false);
    r = __builtin_amdgcn_cvt_pk_fp8_f32(v.z, v.w, r, true);
    return (uint_t)r;
}

// ================= build phase =================
__global__ void k_histm(const int* __restrict__ dst, const int* __restrict__ nm,
                        const int* __restrict__ batch, int* __restrict__ ecnt,
                        int* __restrict__ ncnt, int* __restrict__ pcnt, int EC, int M) {
    int c = blockIdx.x * 256 + threadIdx.x;
    if (c < EC) atomicAdd(&ecnt[dst[c]], 1);
    if (c < M) { atomicAdd(&ncnt[nm[c]], 1); atomicAdd(&pcnt[batch[c]], 1); }
}

// merged scan stage 1: three arrays, block-local exclusive scan (span 1024)
__global__ __launch_bounds__(256) void k_scan1m(const int* __restrict__ inE, int* __restrict__ outE, int nbe, int nE,
                                                const int* __restrict__ inN, int* __restrict__ outN, int nbn, int nN,
                                                const int* __restrict__ inP, int* __restrict__ outP, int nbp, int nP,
                                                int* __restrict__ bsum) {
    __shared__ int ts[256];
    int b = blockIdx.x, t = threadIdx.x;
    const int* in; int* out; int* bs; int lb, n;
    if (b < nbe)            { in = inE; out = outE; bs = bsum;       lb = b;             n = nE; }
    else if (b < nbe + nbn) { in = inN; out = outN; bs = bsum + 256; lb = b - nbe;       n = nN; }
    else                    { in = inP; out = outP; bs = bsum + 512; lb = b - nbe - nbn; n = nP; }
    int base = lb * 1024 + t * 4;
    int v0 = base + 0 < n ? in[base + 0] : 0;
    int v1 = base + 1 < n ? in[base + 1] : 0;
    int v2 = base + 2 < n ? in[base + 2] : 0;
    int v3 = base + 3 < n ? in[base + 3] : 0;
    int tot = v0 + v1 + v2 + v3;
    ts[t] = tot; __syncthreads();
    for (int off = 1; off < 256; off <<= 1) {
        int x = (t >= off) ? ts[t - off] : 0; __syncthreads();
        ts[t] += x; __syncthreads();
    }
    int ex = ts[t] - tot;
    if (base + 0 < n) out[base + 0] = ex;
    if (base + 1 < n) out[base + 1] = ex + v0;
    if (base + 2 < n) out[base + 2] = ex + v0 + v1;
    if (base + 3 < n) out[base + 3] = ex + v0 + v1 + v2;
    if (t == 255) bs[lb] = ts[255];
}

// stage 2: 3 blocks, parallel in-place exclusive scan of <=1024 block sums
__global__ __launch_bounds__(256) void k_scan2m(int* __restrict__ bsum, int nbe, int nbn, int nbp) {
    __shared__ int ts[256];
    int b = blockIdx.x, t = threadIdx.x;
    int* a; int n;
    if (b == 0)      { a = bsum;       n = nbe; }
    else if (b == 1) { a = bsum + 256; n = nbn; }
    else             { a = bsum + 512; n = nbp; }
    int base = t * 4;
    int v0 = base + 0 < n ? a[base + 0] : 0;
    int v1 = base + 1 < n ? a[base + 1] : 0;
    int v2 = base + 2 < n ? a[base + 2] : 0;
    int v3 = base + 3 < n ? a[base + 3] : 0;
    int tot = v0 + v1 + v2 + v3;
    ts[t] = tot; __syncthreads();
    for (int off = 1; off < 256; off <<= 1) {
        int x = (t >= off) ? ts[t - off] : 0; __syncthreads();
        ts[t] += x; __syncthreads();
    }
    int ex = ts[t] - tot;
    if (base + 0 < n) a[base + 0] = ex;
    if (base + 1 < n) a[base + 1] = ex + v0;
    if (base + 2 < n) a[base + 2] = ex + v0 + v1;
    if (base + 3 < n) a[base + 3] = ex + v0 + v1 + v2;
}

__global__ void k_scan3m(int* __restrict__ outE, int* __restrict__ outN, int* __restrict__ outP,
                         const int* __restrict__ bsum, int nE, int nN, int nP) {
    int i = blockIdx.x * 256 + threadIdx.x;
    if (i < nE) { outE[i] += bsum[i >> 10]; return; }
    i -= nE;
    if (i < nN) { outN[i] += bsum[256 + (i >> 10)]; return; }
    i -= nN;
    if (i < nP) { outP[i] += bsum[512 + (i >> 10)]; }
}

// merged scatter: edge CSR payloads (packed int2) + node copy lists + pre-gathered batch
__global__ void k_scatterm(const int* __restrict__ dst, const int* __restrict__ src,
                           const int* __restrict__ em, const int* __restrict__ nm,
                           const int* __restrict__ batch,
                           int* __restrict__ ecur, int2* __restrict__ se,
                           int* __restrict__ ncur, int* __restrict__ mlist, int* __restrict__ pb,
                           int EC, int M) {
    int c = blockIdx.x * 256 + threadIdx.x;
    if (c < EC) {
        int p = atomicAdd(&ecur[dst[c]], 1);
        se[p] = make_int2(nm[src[c]], em[c]);
    }
    if (c < M) {
        int p = atomicAdd(&ncur[nm[c]], 1);
        mlist[p] = c;
        pb[p] = batch[c];
    }
}

// merged converts: ea->fp8 (contiguous), x->bf16, Wg->bf16 transposed, Wu->bf16 transposed
__global__ void k_convm(const float* __restrict__ ea, uint_t* __restrict__ eab4, int EA4,
                        const float* __restrict__ x, ushort_t* __restrict__ xb, int NX8,
                        const float* __restrict__ Wg, ushort_t* __restrict__ Wtb, int NW,
                        const float* __restrict__ Wu, ushort_t* __restrict__ Wub, int NW2) {
    int i = blockIdx.x * 256 + threadIdx.x;
    if (i < EA4) {  // 4 f32 -> packed fp8x4 per thread, contiguous stream
        f4 v = *((const f4*)ea + (size_t)i);
        eab4[i] = f4_to_fp8x4(v);
        return;
    }
    i -= EA4;
    if (i < NX8) {
        const f4* p = (const f4*)x + (size_t)i * 2;
        f4 v0 = p[0], v1 = p[1];
        ushort4 o0, o1;
        o0.x = f2b(v0.x); o0.y = f2b(v0.y); o0.z = f2b(v0.z); o0.w = f2b(v0.w);
        o1.x = f2b(v1.x); o1.y = f2b(v1.y); o1.z = f2b(v1.z); o1.w = f2b(v1.w);
        *(ushort4*)(xb + (size_t)i * 8) = o0;
        *(ushort4*)(xb + (size_t)i * 8 + 4) = o1;
        return;
    }
    i -= NX8;
    if (i < NW) {
        int l = i >> 14, rem = i & 16383;
        int col = rem >> 7, k = rem & 127;
        Wtb[(size_t)l * 16384 + col * 128 + k] = f2b(Wg[(size_t)l * 16384 + k * 128 + col]);
        return;
    }
    i -= NW;
    if (i < NW2) {
        int l = i >> 14, rem = i & 16383;
        int col = rem >> 7, k = rem & 127;
        Wub[(size_t)l * 16384 + col * 128 + k] = f2b(Wu[(size_t)l * 16384 + k * 128 + col]);
    }
}

// ================= compute phase =================
// aggb[d] = bf16( (1+eps)*h[nm[d]] + sum relu(h[se.x] + fp8dec(eab4[se.y])) )
// 16 lanes/row, 16B loads; packed int2 edge indices; 4x unrolled gathers.
__global__ __launch_bounds__(256) void k_edge(const ushort_t* __restrict__ hnb,
                                              const uint_t* __restrict__ eab4,
                                              const int* __restrict__ nm, const int2* __restrict__ se,
                                              const int* __restrict__ eend, const int* __restrict__ ecnt,
                                              ushort_t* __restrict__ aggb,
                                              const float* __restrict__ eps, int layer, int M) {
    int idx = blockIdx.x * 256 + threadIdx.x;
    int d = idx >> 4, j = idx & 15;   // j: 8-col chunk
    if (d >= M) return;
    float s = 1.0f + eps[layer];
    ushort8 hb = *(const ushort8*)(hnb + (size_t)nm[d] * D + j * 8);
    float acc[8];
#pragma unroll
    for (int q = 0; q < 8; q++) acc[q] = b2f(hb[q]) * s;
    int kn = eend[d], k0 = kn - ecnt[d];
    int k = k0;
    for (; k + 4 <= kn; k += 4) {
        int2 se0 = se[k], se1 = se[k + 1], se2 = se[k + 2], se3 = se[k + 3];
        uint2 p0 = *(const uint2*)(eab4 + (size_t)se0.y * 32 + j * 2);
        uint2 p1 = *(const uint2*)(eab4 + (size_t)se1.y * 32 + j * 2);
        uint2 p2 = *(const uint2*)(eab4 + (size_t)se2.y * 32 + j * 2);
        uint2 p3 = *(const uint2*)(eab4 + (size_t)se3.y * 32 + j * 2);
        ushort8 h0 = *(const ushort8*)(hnb + (size_t)se0.x * D + j * 8);
        ushort8 h1 = *(const ushort8*)(hnb + (size_t)se1.x * D + j * 8);
        ushort8 h2 = *(const ushort8*)(hnb + (size_t)se2.x * D + j * 8);
        ushort8 h3 = *(const ushort8*)(hnb + (size_t)se3.x * D + j * 8);
        f4 e0a = fp8x4_to_f4(p0.x), e0b = fp8x4_to_f4(p0.y);
        f4 e1a = fp8x4_to_f4(p1.x), e1b = fp8x4_to_f4(p1.y);
        f4 e2a = fp8x4_to_f4(p2.x), e2b = fp8x4_to_f4(p2.y);
        f4 e3a = fp8x4_to_f4(p3.x), e3b = fp8x4_to_f4(p3.y);
        acc[0] += (fmaxf(b2f(h0[0]) + e0a.x, 0.f) + fmaxf(b2f(h1[0]) + e1a.x, 0.f))
                + (fmaxf(b2f(h2[0]) + e2a.x, 0.f) + fmaxf(b2f(h3[0]) + e3a.x, 0.f));
        acc[1] += (fmaxf(b2f(h0[1]) + e0a.y, 0.f) + fmaxf(b2f(h1[1]) + e1a.y, 0.f))
                + (fmaxf(b2f(h2[1]) + e2a.y, 0.f) + fmaxf(b2f(h3[1]) + e3a.y, 0.f));
        acc[2] += (fmaxf(b2f(h0[2]) + e0a.z, 0.f) + fmaxf(b2f(h1[2]) + e1a.z, 0.f))
                + (fmaxf(b2f(h2[2]) + e2a.z, 0.f) + fmaxf(b2f(h3[2]) + e3a.z, 0.f));
        acc[3] += (fmaxf(b2f(h0[3]) + e0a.w, 0.f) + fmaxf(b2f(h1[3]) + e1a.w, 0.f))
                + (fmaxf(b2f(h2[3]) + e2a.w, 0.f) + fmaxf(b2f(h3[3]) + e3a.w, 0.f));
        acc[4] += (fmaxf(b2f(h0[4]) + e0b.x, 0.f) + fmaxf(b2f(h1[4]) + e1b.x, 0.f))
                + (fmaxf(b2f(h2[4]) + e2b.x, 0.f) + fmaxf(b2f(h3[4]) + e3b.x, 0.f));
        acc[5] += (fmaxf(b2f(h0[5]) + e0b.y, 0.f) + fmaxf(b2f(h1[5]) + e1b.y, 0.f))
                + (fmaxf(b2f(h2[5]) + e2b.y, 0.f) + fmaxf(b2f(h3[5]) + e3b.y, 0.f));
        acc[6] += (fmaxf(b2f(h0[6]) + e0b.z, 0.f) + fmaxf(b2f(h1[6]) + e1b.z, 0.f))
                + (fmaxf(b2f(h2[6]) + e2b.z, 0.f) + fmaxf(b2f(h3[6]) + e3b.z, 0.f));
        acc[7] += (fmaxf(b2f(h0[7]) + e0b.w, 0.f) + fmaxf(b2f(h1[7]) + e1b.w, 0.f))
                + (fmaxf(b2f(h2[7]) + e2b.w, 0.f) + fmaxf(b2f(h3[7]) + e3b.w, 0.f));
    }
    for (; k < kn; k++) {
        int2 se0 = se[k];
        uint2 p0 = *(const uint2*)(eab4 + (size_t)se0.y * 32 + j * 2);
        ushort8 h0 = *(const ushort8*)(hnb + (size_t)se0.x * D + j * 8);
        f4 e0a = fp8x4_to_f4(p0.x), e0b = fp8x4_to_f4(p0.y);
        acc[0] += fmaxf(b2f(h0[0]) + e0a.x, 0.f);
        acc[1] += fmaxf(b2f(h0[1]) + e0a.y, 0.f);
        acc[2] += fmaxf(b2f(h0[2]) + e0a.z, 0.f);
        acc[3] += fmaxf(b2f(h0[3]) + e0a.w, 0.f);
        acc[4] += fmaxf(b2f(h0[4]) + e0b.x, 0.f);
        acc[5] += fmaxf(b2f(h0[5]) + e0b.y, 0.f);
        acc[6] += fmaxf(b2f(h0[6]) + e0b.z, 0.f);
        acc[7] += fmaxf(b2f(h0[7]) + e0b.w, 0.f);
    }
    ushort8 o;
#pragma unroll
    for (int q = 0; q < 8; q++) o[q] = f2b(acc[q]);
    *(ushort8*)(aggb + (size_t)d * D + j * 8) = o;
}

// block per patch: pmean[p] = bf16(mean over contiguous aggb rows)
__global__ __launch_bounds__(256) void k_patch_agg(const ushort_t* __restrict__ aggb,
                                                   const int* __restrict__ pstart, const int* __restrict__ pcnt,
                                                   ushort_t* __restrict__ pmean) {
    __shared__ f4 red[256];
    int p = blockIdx.x;
    int t = threadIdx.x, j = t & 31, r = t >> 5;
    int s0 = pstart[p], c = pcnt[p];
    f4 acc = make_float4(0.f, 0.f, 0.f, 0.f);
    for (int k = r; k < c; k += 8) {
        ushort4 ab = *(const ushort4*)(aggb + (size_t)(s0 + k) * D + j * 4);
        acc.x += b2f(ab.x); acc.y += b2f(ab.y); acc.z += b2f(ab.z); acc.w += b2f(ab.w);
    }
    red[t] = acc; __syncthreads();
    for (int step = 4; step >= 1; step >>= 1) {
        if (r < step) f4add(red[t], red[t + 32 * step]);
        __syncthreads();
    }
    if (r == 0) {
        f4 a = red[j];
        float inv = 1.0f / fmaxf((float)c, 1.0f);
        ushort4 o;
        o.x = f2b(a.x * inv); o.y = f2b(a.y * inv); o.z = f2b(a.z * inv); o.w = f2b(a.w * inv);
        *(ushort4*)(pmean + (size_t)p * D + j * 4) = o;
    }
}

// MFMA patch transform (64 patches/block):
//   mid = pmean @ Wg[l] + bg[l]    (bf16 in LDS)
//   layer<3 : pmu = bf16(relu(mid @ Wu[l] + bu[l]))
//   layer==3: out = mid (f32)
__global__ __launch_bounds__(256) void k_ptf_mfma(const ushort_t* __restrict__ pmean,
                                                  const ushort_t* __restrict__ Wtb, const float* __restrict__ bg,
                                                  const ushort_t* __restrict__ Wub, const float* __restrict__ bu,
                                                  ushort_t* __restrict__ pmu, float* __restrict__ outv,
                                                  int P_, int layer) {
    __shared__ ushort_t Wl[128 * 136];
    __shared__ ushort_t midl[64 * 136];
    int t = threadIdx.x;
    const ushort_t* W = Wtb + (size_t)layer * D * D;
#pragma unroll
    for (int i = 0; i < 8; i++) {
        int cid = t + i * 256;
        int col = cid >> 4, kc = (cid & 15) * 8;
        *(short8*)&Wl[col * 136 + kc] = *(const short8*)(W + col * 128 + kc);
    }
    __syncthreads();
    int w = t >> 6, lane = t & 63;
    int r16 = lane & 15, kg = lane >> 4;
    int rowbase = blockIdx.x * 64 + w * 16;
    size_t arow = (size_t)min(rowbase + r16, P_ - 1) * D;
    short8 a0 = *(const short8*)(pmean + arow + 0 + kg * 8);
    short8 a1 = *(const short8*)(pmean + arow + 32 + kg * 8);
    short8 a2 = *(const short8*)(pmean + arow + 64 + kg * 8);
    short8 a3 = *(const short8*)(pmean + arow + 96 + kg * 8);
#pragma unroll
    for (int c = 0; c < 8; c++) {
        const ushort_t* wp = &Wl[(c * 16 + r16) * 136 + kg * 8];
        short8 b0 = *(const short8*)(wp + 0);
        short8 b1 = *(const short8*)(wp + 32);
        short8 b2 = *(const short8*)(wp + 64);
        short8 b3 = *(const short8*)(wp + 96);
        f32x4 acc = (f32x4){0.f, 0.f, 0.f, 0.f};
        acc = __builtin_amdgcn_mfma_f32_16x16x32_bf16(a0, b0, acc, 0, 0, 0);
        acc = __builtin_amdgcn_mfma_f32_16x16x32_bf16(a1, b1, acc, 0, 0, 0);
        acc = __builtin_amdgcn_mfma_f32_16x16x32_bf16(a2, b2, acc, 0, 0, 0);
        acc = __builtin_amdgcn_mfma_f32_16x16x32_bf16(a3, b3, acc, 0, 0, 0);
        int gcol = c * 16 + r16;
        float bias = bg[layer * D + gcol];
#pragma unroll
        for (int q = 0; q < 4; q++) {
            int lrow = w * 16 + kg * 4 + q;
            float v = acc[q] + bias;
            if (layer == 3) {
                int grow = rowbase - w * 16 + lrow;  // = blockIdx*64 + lrow
                if (grow < P_) outv[(size_t)grow * D + gcol] = v;
            } else {
                midl[lrow * 136 + gcol] = f2b(v);
            }
        }
    }
    if (layer == 3) return;
    __syncthreads();
    // re-stage Wl with Wu^T
    const ushort_t* W2 = Wub + (size_t)layer * D * D;
#pragma unroll
    for (int i = 0; i < 8; i++) {
        int cid = t + i * 256;
        int col = cid >> 4, kc = (cid & 15) * 8;
        *(short8*)&Wl[col * 136 + kc] = *(const short8*)(W2 + col * 128 + kc);
    }
    __syncthreads();
    const ushort_t* mp = &midl[(w * 16 + r16) * 136 + kg * 8];
    short8 m0 = *(const short8*)(mp + 0);
    short8 m1 = *(const short8*)(mp + 32);
    short8 m2 = *(const short8*)(mp + 64);
    short8 m3 = *(const short8*)(mp + 96);
#pragma unroll
    for (int c = 0; c < 8; c++) {
        const ushort_t* wp = &Wl[(c * 16 + r16) * 136 + kg * 8];
        short8 b0 = *(const short8*)(wp + 0);
        short8 b1 = *(const short8*)(wp + 32);
        short8 b2 = *(const short8*)(wp + 64);
        short8 b3 = *(const short8*)(wp + 96);
        f32x4 acc = (f32x4){0.f, 0.f, 0.f, 0.f};
        acc = __builtin_amdgcn_mfma_f32_16x16x32_bf16(m0, b0, acc, 0, 0, 0);
        acc = __builtin_amdgcn_mfma_f32_16x16x32_bf16(m1, b1, acc, 0, 0, 0);
        acc = __builtin_amdgcn_mfma_f32_16x16x32_bf16(m2, b2, acc, 0, 0, 0);
        acc = __builtin_amdgcn_mfma_f32_16x16x32_bf16(m3, b3, acc, 0, 0, 0);
        int gcol = c * 16 + r16;
        float bias = bu[layer * D + gcol];
#pragma unroll
        for (int q = 0; q < 4; q++) {
            int grow = blockIdx.x * 64 + w * 16 + kg * 4 + q;
            if (grow < P_)
                pmu[(size_t)grow * D + gcol] = f2b(fmaxf(acc[q] + bias, 0.f));
        }
    }
}

// per node: naggb[n] = bf16(mean over copies of aggb); pmusum[n] = bf16(mean of pmu[pb])
// 16 lanes/node, 16B loads; pmu now bf16.
__global__ __launch_bounds__(256) void k_nagg(const ushort_t* __restrict__ aggb,
                                              const ushort_t* __restrict__ pmu,
                                              const int* __restrict__ pb, const int* __restrict__ mlist,
                                              const int* __restrict__ nend, const int* __restrict__ ncnt,
                                              ushort_t* __restrict__ naggb, ushort_t* __restrict__ pmusum,
                                              int N) {
    int idx = blockIdx.x * 256 + threadIdx.x;
    int n = idx >> 4, j = idx & 15;
    if (n >= N) return;
    int kn = nend[n], c = ncnt[n], s0 = kn - c;
    float sa[8] = {0.f, 0.f, 0.f, 0.f, 0.f, 0.f, 0.f, 0.f};
    float sp[8] = {0.f, 0.f, 0.f, 0.f, 0.f, 0.f, 0.f, 0.f};
    for (int k = 0; k < c; k++) {
        int m = mlist[s0 + k];
        int pbv = pb[s0 + k];
        ushort8 ab = *(const ushort8*)(aggb + (size_t)m * D + j * 8);
        ushort8 pv = *(const ushort8*)(pmu + (size_t)pbv * D + j * 8);
#pragma unroll
        for (int q = 0; q < 8; q++) { sa[q] += b2f(ab[q]); sp[q] += b2f(pv[q]); }
    }
    float inv = 1.0f / fmaxf((float)c, 1.0f);
    ushort8 o, q8;
#pragma unroll
    for (int q = 0; q < 8; q++) { o[q] = f2b(sa[q] * inv); q8[q] = f2b(sp[q] * inv); }
    *(ushort8*)(naggb + (size_t)n * D + j * 8) = o;
    *(ushort8*)(pmusum + (size_t)n * D + j * 8) = q8;
}

// hnb[N,128] = bf16( naggb(bf16) @ W[l] + b[l] + pmusum ), MFMA 16x16x32, 64 rows/block
__global__ __launch_bounds__(256) void k_nup(const ushort_t* __restrict__ naggb,
                                             const ushort_t* __restrict__ Wtb,
                                             const float* __restrict__ bg,
                                             const ushort_t* __restrict__ pmusum,
                                             ushort_t* __restrict__ hnb, int N, int layer) {
    __shared__ ushort_t Wl[128 * 136];  // [col][k] padded
    const ushort_t* W = Wtb + (size_t)layer * D * D;
    int t = threadIdx.x;
#pragma unroll
    for (int i = 0; i < 8; i++) {
        int cid = t + i * 256;
        int col = cid >> 4, kc = (cid & 15) * 8;
        *(short8*)&Wl[col * 136 + kc] = *(const short8*)(W + col * 128 + kc);
    }
    __syncthreads();
    int w = t >> 6, lane = t & 63;
    int r16 = lane & 15, kg = lane >> 4;
    int rowbase = blockIdx.x * 64 + w * 16;
    size_t arow = (size_t)min(rowbase + r16, N - 1) * D;
    short8 a0 = *(const short8*)(naggb + arow + 0 + kg * 8);
    short8 a1 = *(const short8*)(naggb + arow + 32 + kg * 8);
    short8 a2 = *(const short8*)(naggb + arow + 64 + kg * 8);
    short8 a3 = *(const short8*)(naggb + arow + 96 + kg * 8);
#pragma unroll
    for (int c = 0; c < 8; c++) {
        const ushort_t* wp = &Wl[(c * 16 + r16) * 136 + kg * 8];
        short8 b0 = *(const short8*)(wp + 0);
        short8 b1 = *(const short8*)(wp + 32);
        short8 b2 = *(const short8*)(wp + 64);
        short8 b3 = *(const short8*)(wp + 96);
        f32x4 acc = (f32x4){0.f, 0.f, 0.f, 0.f};
        acc = __builtin_amdgcn_mfma_f32_16x16x32_bf16(a0, b0, acc, 0, 0, 0);
        acc = __builtin_amdgcn_mfma_f32_16x16x32_bf16(a1, b1, acc, 0, 0, 0);
        acc = __builtin_amdgcn_mfma_f32_16x16x32_bf16(a2, b2, acc, 0, 0, 0);
        acc = __builtin_amdgcn_mfma_f32_16x16x32_bf16(a3, b3, acc, 0, 0, 0);
        int gcol = c * 16 + r16;
        float bias = bg[layer * D + gcol];
#pragma unroll
        for (int q = 0; q < 4; q++) {
            int grow = rowbase + kg * 4 + q;
            if (grow < N)
                hnb[(size_t)grow * D + gcol] =
                    f2b(acc[q] + bias + b2f(pmusum[(size_t)grow * D + gcol]));
        }
    }
}

extern "C" void kernel_launch(void* const* d_in, const int* in_sizes, int n_in,
                              void* d_out, int out_size, void* d_ws, size_t ws_size,
                              hipStream_t stream) {
    const float* x    = (const float*)d_in[0];
    const float* ea   = (const float*)d_in[1];
    const int* nm     = (const int*)d_in[2];
    const int* em     = (const int*)d_in[3];
    const int* cs     = (const int*)d_in[4];
    const int* batch  = (const int*)d_in[5];
    const float* Wg   = (const float*)d_in[7];
    const float* bg   = (const float*)d_in[8];
    const float* eps  = (const float*)d_in[9];
    const float* Wu   = (const float*)d_in[10];
    const float* bu   = (const float*)d_in[11];
    float* out = (float*)d_out;

    int N  = in_sizes[0] / D;
    int E  = in_sizes[1] / D;
    int M  = in_sizes[2];
    int EC = in_sizes[3];
    int P  = out_size / D;
    const int* src = cs;
    const int* dst = cs + EC;

    // workspace carve (256B aligned)
    char* base = (char*)d_ws;
    size_t off = 0;
    auto carve = [&](size_t bytes) { void* p = base + off; off += (bytes + 255) & ~(size_t)255; return p; };
    ushort_t* aggb   = (ushort_t*)carve((size_t)M * D * 2);
    uint_t*   eab4   = (uint_t*)carve((size_t)E * D);     // fp8 e4m3: 128 B/row, E-indexed
    ushort_t* xb     = (ushort_t*)carve((size_t)N * D * 2);
    ushort_t* Wtb    = (ushort_t*)carve((size_t)4 * D * D * 2);
    ushort_t* Wub    = (ushort_t*)carve((size_t)3 * D * D * 2);
    ushort_t* hnb    = (ushort_t*)carve((size_t)N * D * 2);
    ushort_t* naggb  = (ushort_t*)carve((size_t)N * D * 2);
    ushort_t* pmusum = (ushort_t*)carve((size_t)N * D * 2);
    ushort_t* pmean  = (ushort_t*)carve((size_t)P * D * 2);
    ushort_t* pmu    = (ushort_t*)carve((size_t)P * D * 2);
    int* cntblk = (int*)carve((size_t)(M + N + P) * 4);
    int* ecnt = cntblk, *ncnt = cntblk + M, *pcnt = cntblk + M + N;
    int* ecur   = (int*)carve((size_t)M * 4);
    int* ncur   = (int*)carve((size_t)N * 4);
    int2* se    = (int2*)carve((size_t)EC * 8);
    int* mlist  = (int*)carve((size_t)M * 4);
    int* pb     = (int*)carve((size_t)M * 4);
    int* pstart = (int*)carve((size_t)P * 4);
    int* bsum   = (int*)carve(768 * 4);
    if (ws_size < off) return;

    // ---- build (reused across layers) ----
    hipMemsetAsync(cntblk, 0, (size_t)(M + N + P) * sizeof(int), stream);
    int mxEM = EC > M ? EC : M;
    k_histm<<<(mxEM + 255) / 256, 256, 0, stream>>>(dst, nm, batch, ecnt, ncnt, pcnt, EC, M);

    int nbe = (M + 1023) / 1024, nbn = (N + 1023) / 1024, nbp = (P + 1023) / 1024;
    k_scan1m<<<nbe + nbn + nbp, 256, 0, stream>>>(ecnt, ecur, nbe, M,
                                                  ncnt, ncur, nbn, N,
                                                  pcnt, pstart, nbp, P, bsum);
    k_scan2m<<<3, 256, 0, stream>>>(bsum, nbe, nbn, nbp);
    k_scan3m<<<(M + N + P + 255) / 256, 256, 0, stream>>>(ecur, ncur, pstart, bsum, M, N, P);

    k_scatterm<<<(mxEM + 255) / 256, 256, 0, stream>>>(dst, src, em, nm, batch,
                                                       ecur, se, ncur, mlist, pb, EC, M);
    int EA4 = E * D / 4, NX8 = N * D / 8, NW = 4 * D * D, NW2 = 3 * D * D;
    k_convm<<<(EA4 + NX8 + NW + NW2 + 255) / 256, 256, 0, stream>>>(ea, eab4, EA4, x, xb, NX8,
                                                                    Wg, Wtb, NW, Wu, Wub, NW2);

    // ---- compute ----
    int mb = (M * 16 + 255) / 256;
    int nb = (N * 16 + 255) / 256;
    int pblk = (P + 63) / 64;
    for (int i = 0; i < 4; i++) {
        const ushort_t* hnp = (i == 0) ? xb : hnb;
        if (i > 0) {
            k_nagg<<<nb, 256, 0, stream>>>(aggb, pmu, pb, mlist,
                                           ncur, ncnt, naggb, pmusum, N);
            k_nup<<<(N + 63) / 64, 256, 0, stream>>>(naggb, Wtb, bg, pmusum, hnb, N, i - 1);
        }
        k_edge<<<mb, 256, 0, stream>>>(hnp, eab4, nm, se, ecur, ecnt, aggb, eps, i, M);
        k_patch_agg<<<P, 256, 0, stream>>>(aggb, pstart, pcnt, pmean);
        k_ptf_mfma<<<pblk, 256, 0, stream>>>(pmean, Wtb, bg, Wub, bu, pmu, out, P, i);
    }
}

// Round 13
// 599.474 us; speedup vs baseline: 1.0310x; 1.0310x over previous
//
#include <hip/hip_runtime.h>
#include <hip/hip_bf16.h>

#define D 128
#define DV 32   // float4 per row

typedef float4 f4;
typedef unsigned short ushort_t;
typedef unsigned int uint_t;
typedef __attribute__((ext_vector_type(8))) short short8;
typedef __attribute__((ext_vector_type(8))) unsigned short ushort8;
typedef __attribute__((ext_vector_type(4))) float f32x4;
typedef __attribute__((ext_vector_type(2))) float f32x2;

__device__ __forceinline__ void f4add(f4& a, const f4& b) {
    a.x += b.x; a.y += b.y; a.z += b.z; a.w += b.w;
}
__device__ __forceinline__ float b2f(ushort_t u) {
    union { unsigned int i; float f; } v; v.i = ((unsigned int)u) << 16; return v.f;
}
__device__ __forceinline__ ushort_t f2b(float f) {
    __hip_bfloat16 b = __float2bfloat16(f);
    return *reinterpret_cast<ushort_t*>(&b);
}
// fp8 e4m3 (OCP on gfx950) hw converts
__device__ __forceinline__ f4 fp8x4_to_f4(uint_t v) {
    f32x2 lo = __builtin_amdgcn_cvt_pk_f32_fp8((int)v, false);
    f32x2 hi = __builtin_amdgcn_cvt_pk_f32_fp8((int)v, true);
    return make_float4(lo[0], lo[1], hi[0], hi[1]);
}
__device__ __forceinline__ uint_t f4_to_fp8x4(f4 v) {
    int r = 0;
    r = __builtin_amdgcn_cvt_pk_fp8_f32(v.x, v.y, r, false);
    r = __builtin_amdgcn_cvt_pk_fp8_f32(v.z, v.w, r, true);
    return (uint_t)r;
}

// ================= build phase =================
__global__ void k_histm(const int* __restrict__ dst, const int* __restrict__ nm,
                        const int* __restrict__ batch, int* __restrict__ ecnt,
                        int* __restrict__ ncnt, int* __restrict__ pcnt, int EC, int M) {
    int c = blockIdx.x * 256 + threadIdx.x;
    if (c < EC) atomicAdd(&ecnt[dst[c]], 1);
    if (c < M) { atomicAdd(&ncnt[nm[c]], 1); atomicAdd(&pcnt[batch[c]], 1); }
}

// merged scan stage 1: three arrays, block-local exclusive scan (span 1024)
__global__ __launch_bounds__(256) void k_scan1m(const int* __restrict__ inE, int* __restrict__ outE, int nbe, int nE,
                                                const int* __restrict__ inN, int* __restrict__ outN, int nbn, int nN,
                                                const int* __restrict__ inP, int* __restrict__ outP, int nbp, int nP,
                                                int* __restrict__ bsum) {
    __shared__ int ts[256];
    int b = blockIdx.x, t = threadIdx.x;
    const int* in; int* out; int* bs; int lb, n;
    if (b < nbe)            { in = inE; out = outE; bs = bsum;       lb = b;             n = nE; }
    else if (b < nbe + nbn) { in = inN; out = outN; bs = bsum + 256; lb = b - nbe;       n = nN; }
    else                    { in = inP; out = outP; bs = bsum + 512; lb = b - nbe - nbn; n = nP; }
    int base = lb * 1024 + t * 4;
    int v0 = base + 0 < n ? in[base + 0] : 0;
    int v1 = base + 1 < n ? in[base + 1] : 0;
    int v2 = base + 2 < n ? in[base + 2] : 0;
    int v3 = base + 3 < n ? in[base + 3] : 0;
    int tot = v0 + v1 + v2 + v3;
    ts[t] = tot; __syncthreads();
    for (int off = 1; off < 256; off <<= 1) {
        int x = (t >= off) ? ts[t - off] : 0; __syncthreads();
        ts[t] += x; __syncthreads();
    }
    int ex = ts[t] - tot;
    if (base + 0 < n) out[base + 0] = ex;
    if (base + 1 < n) out[base + 1] = ex + v0;
    if (base + 2 < n) out[base + 2] = ex + v0 + v1;
    if (base + 3 < n) out[base + 3] = ex + v0 + v1 + v2;
    if (t == 255) bs[lb] = ts[255];
}

// stage 2: 3 blocks, parallel in-place exclusive scan of <=1024 block sums
__global__ __launch_bounds__(256) void k_scan2m(int* __restrict__ bsum, int nbe, int nbn, int nbp) {
    __shared__ int ts[256];
    int b = blockIdx.x, t = threadIdx.x;
    int* a; int n;
    if (b == 0)      { a = bsum;       n = nbe; }
    else if (b == 1) { a = bsum + 256; n = nbn; }
    else             { a = bsum + 512; n = nbp; }
    int base = t * 4;
    int v0 = base + 0 < n ? a[base + 0] : 0;
    int v1 = base + 1 < n ? a[base + 1] : 0;
    int v2 = base + 2 < n ? a[base + 2] : 0;
    int v3 = base + 3 < n ? a[base + 3] : 0;
    int tot = v0 + v1 + v2 + v3;
    ts[t] = tot; __syncthreads();
    for (int off = 1; off < 256; off <<= 1) {
        int x = (t >= off) ? ts[t - off] : 0; __syncthreads();
        ts[t] += x; __syncthreads();
    }
    int ex = ts[t] - tot;
    if (base + 0 < n) a[base + 0] = ex;
    if (base + 1 < n) a[base + 1] = ex + v0;
    if (base + 2 < n) a[base + 2] = ex + v0 + v1;
    if (base + 3 < n) a[base + 3] = ex + v0 + v1 + v2;
}

__global__ void k_scan3m(int* __restrict__ outE, int* __restrict__ outN, int* __restrict__ outP,
                         const int* __restrict__ bsum, int nE, int nN, int nP) {
    int i = blockIdx.x * 256 + threadIdx.x;
    if (i < nE) { outE[i] += bsum[i >> 10]; return; }
    i -= nE;
    if (i < nN) { outN[i] += bsum[256 + (i >> 10)]; return; }
    i -= nN;
    if (i < nP) { outP[i] += bsum[512 + (i >> 10)]; }
}

// merged scatter: edge CSR payloads (packed int2) + node copy lists + pre-gathered batch
__global__ void k_scatterm(const int* __restrict__ dst, const int* __restrict__ src,
                           const int* __restrict__ em, const int* __restrict__ nm,
                           const int* __restrict__ batch,
                           int* __restrict__ ecur, int2* __restrict__ se,
                           int* __restrict__ ncur, int* __restrict__ mlist, int* __restrict__ pb,
                           int EC, int M) {
    int c = blockIdx.x * 256 + threadIdx.x;
    if (c < EC) {
        int p = atomicAdd(&ecur[dst[c]], 1);
        se[p] = make_int2(nm[src[c]], em[c]);
    }
    if (c < M) {
        int p = atomicAdd(&ncur[nm[c]], 1);
        mlist[p] = c;
        pb[p] = batch[c];
    }
}

// merged converts: ea->fp8 (contiguous), x->bf16, W->bf16 transposed
__global__ void k_convm(const float* __restrict__ ea, uint_t* __restrict__ eab4, int EA4,
                        const float* __restrict__ x, ushort_t* __restrict__ xb, int NX8,
                        const float* __restrict__ Wg, ushort_t* __restrict__ Wtb, int NW) {
    int i = blockIdx.x * 256 + threadIdx.x;
    if (i < EA4) {  // 4 f32 -> packed fp8x4 per thread, contiguous stream
        f4 v = *((const f4*)ea + (size_t)i);
        eab4[i] = f4_to_fp8x4(v);
        return;
    }
    i -= EA4;
    if (i < NX8) {
        const f4* p = (const f4*)x + (size_t)i * 2;
        f4 v0 = p[0], v1 = p[1];
        ushort4 o0, o1;
        o0.x = f2b(v0.x); o0.y = f2b(v0.y); o0.z = f2b(v0.z); o0.w = f2b(v0.w);
        o1.x = f2b(v1.x); o1.y = f2b(v1.y); o1.z = f2b(v1.z); o1.w = f2b(v1.w);
        *(ushort4*)(xb + (size_t)i * 8) = o0;
        *(ushort4*)(xb + (size_t)i * 8 + 4) = o1;
        return;
    }
    i -= NX8;
    if (i < NW) {
        int l = i >> 14, rem = i & 16383;
        int col = rem >> 7, k = rem & 127;
        Wtb[(size_t)l * 16384 + col * 128 + k] = f2b(Wg[(size_t)l * 16384 + k * 128 + col]);
    }
}

// ================= compute phase =================
// aggb[d] = bf16( (1+eps)*h[nm[d]] + sum relu(h[se.x] + fp8dec(eab4[se.y])) )
// 16 lanes/row, 16B loads; packed int2 edge indices.
__global__ __launch_bounds__(256) void k_edge(const ushort_t* __restrict__ hnb,
                                              const uint_t* __restrict__ eab4,
                                              const int* __restrict__ nm, const int2* __restrict__ se,
                                              const int* __restrict__ eend, const int* __restrict__ ecnt,
                                              ushort_t* __restrict__ aggb,
                                              const float* __restrict__ eps, int layer, int M) {
    int idx = blockIdx.x * 256 + threadIdx.x;
    int d = idx >> 4, j = idx & 15;   // j: 8-col chunk
    if (d >= M) return;
    float s = 1.0f + eps[layer];
    ushort8 hb = *(const ushort8*)(hnb + (size_t)nm[d] * D + j * 8);
    float acc[8];
#pragma unroll
    for (int q = 0; q < 8; q++) acc[q] = b2f(hb[q]) * s;
    int kn = eend[d], k0 = kn - ecnt[d];
    int k = k0;
    for (; k + 2 <= kn; k += 2) {
        int2 se0 = se[k], se1 = se[k + 1];
        uint2 p0 = *(const uint2*)(eab4 + (size_t)se0.y * 32 + j * 2);
        uint2 p1 = *(const uint2*)(eab4 + (size_t)se1.y * 32 + j * 2);
        ushort8 h0 = *(const ushort8*)(hnb + (size_t)se0.x * D + j * 8);
        ushort8 h1 = *(const ushort8*)(hnb + (size_t)se1.x * D + j * 8);
        f4 e0a = fp8x4_to_f4(p0.x), e0b = fp8x4_to_f4(p0.y);
        f4 e1a = fp8x4_to_f4(p1.x), e1b = fp8x4_to_f4(p1.y);
        acc[0] += fmaxf(b2f(h0[0]) + e0a.x, 0.f) + fmaxf(b2f(h1[0]) + e1a.x, 0.f);
        acc[1] += fmaxf(b2f(h0[1]) + e0a.y, 0.f) + fmaxf(b2f(h1[1]) + e1a.y, 0.f);
        acc[2] += fmaxf(b2f(h0[2]) + e0a.z, 0.f) + fmaxf(b2f(h1[2]) + e1a.z, 0.f);
        acc[3] += fmaxf(b2f(h0[3]) + e0a.w, 0.f) + fmaxf(b2f(h1[3]) + e1a.w, 0.f);
        acc[4] += fmaxf(b2f(h0[4]) + e0b.x, 0.f) + fmaxf(b2f(h1[4]) + e1b.x, 0.f);
        acc[5] += fmaxf(b2f(h0[5]) + e0b.y, 0.f) + fmaxf(b2f(h1[5]) + e1b.y, 0.f);
        acc[6] += fmaxf(b2f(h0[6]) + e0b.z, 0.f) + fmaxf(b2f(h1[6]) + e1b.z, 0.f);
        acc[7] += fmaxf(b2f(h0[7]) + e0b.w, 0.f) + fmaxf(b2f(h1[7]) + e1b.w, 0.f);
    }
    if (k < kn) {
        int2 se0 = se[k];
        uint2 p0 = *(const uint2*)(eab4 + (size_t)se0.y * 32 + j * 2);
        ushort8 h0 = *(const ushort8*)(hnb + (size_t)se0.x * D + j * 8);
        f4 e0a = fp8x4_to_f4(p0.x), e0b = fp8x4_to_f4(p0.y);
        acc[0] += fmaxf(b2f(h0[0]) + e0a.x, 0.f);
        acc[1] += fmaxf(b2f(h0[1]) + e0a.y, 0.f);
        acc[2] += fmaxf(b2f(h0[2]) + e0a.z, 0.f);
        acc[3] += fmaxf(b2f(h0[3]) + e0a.w, 0.f);
        acc[4] += fmaxf(b2f(h0[4]) + e0b.x, 0.f);
        acc[5] += fmaxf(b2f(h0[5]) + e0b.y, 0.f);
        acc[6] += fmaxf(b2f(h0[6]) + e0b.z, 0.f);
        acc[7] += fmaxf(b2f(h0[7]) + e0b.w, 0.f);
    }
    ushort8 o;
#pragma unroll
    for (int q = 0; q < 8; q++) o[q] = f2b(acc[q]);
    *(ushort8*)(aggb + (size_t)d * D + j * 8) = o;
}

// fused per-patch: mean over contiguous aggb rows, then split-K GEMV (all 256 threads):
//   layer<3 : pmu[p] = bf16(relu((mean @ Wg[l] + bg[l]) @ Wu[l] + bu[l]))
//   layer==3: out[p] = mean @ Wg[3] + bg[3]   (f32)
__global__ __launch_bounds__(256) void k_patch_tf(const ushort_t* __restrict__ aggb,
                                                  const int* __restrict__ pstart, const int* __restrict__ pcnt,
                                                  const float* __restrict__ Wg, const float* __restrict__ bg,
                                                  const float* __restrict__ Wu, const float* __restrict__ bu,
                                                  ushort_t* __restrict__ pmu, float* __restrict__ outv, int layer) {
    __shared__ f4 red[256];
    __shared__ float row[D];
    __shared__ float gp[256];
    int p = blockIdx.x;
    int t = threadIdx.x, j = t & 31, r = t >> 5;
    int s0 = pstart[p], c = pcnt[p];
    f4 acc = make_float4(0.f, 0.f, 0.f, 0.f);
    for (int k = r; k < c; k += 8) {
        ushort4 ab = *(const ushort4*)(aggb + (size_t)(s0 + k) * D + j * 4);
        acc.x += b2f(ab.x); acc.y += b2f(ab.y); acc.z += b2f(ab.z); acc.w += b2f(ab.w);
    }
    red[t] = acc; __syncthreads();
    for (int step = 4; step >= 1; step >>= 1) {
        if (r < step) f4add(red[t], red[t + 32 * step]);
        __syncthreads();
    }
    if (r == 0) {
        f4 a = red[j];
        float inv = 1.0f / fmaxf((float)c, 1.0f);
        a.x *= inv; a.y *= inv; a.z *= inv; a.w *= inv;
        *(f4*)&row[j * 4] = a;
    }
    __syncthreads();
    // phase 1 GEMV, K split across two thread-halves
    int col = t & 127, half = t >> 7;
    {
        const float* W = Wg + (size_t)layer * D * D;
        float g = 0.f;
        int kb = half * 64;
#pragma unroll 8
        for (int k = 0; k < 64; k++) g += row[kb + k] * W[(kb + k) * D + col];
        gp[t] = g;
    }
    __syncthreads();
    if (layer == 3) {
        if (t < D) outv[(size_t)p * D + t] = gp[t] + gp[t + 128] + bg[layer * D + t];
        return;
    }
    __shared__ float mid[D];
    if (t < D) mid[t] = gp[t] + gp[t + 128] + bg[layer * D + t];
    __syncthreads();
    {
        const float* W2 = Wu + (size_t)layer * D * D;
        float g = 0.f;
        int kb = half * 64;
#pragma unroll 8
        for (int k = 0; k < 64; k++) g += mid[kb + k] * W2[(kb + k) * D + col];
        gp[t] = g;
    }
    __syncthreads();
    if (t < D) pmu[(size_t)p * D + t] = f2b(fmaxf(gp[t] + gp[t + 128] + bu[layer * D + t], 0.f));
}

// per node: naggb[n] = bf16(mean over copies of aggb); pmusum[n] = bf16(mean of pmu[pb])
// 16 lanes/node, 16B loads; pb contiguous; pmu bf16 (16B gather).
__global__ __launch_bounds__(256) void k_nagg(const ushort_t* __restrict__ aggb,
                                              const ushort_t* __restrict__ pmu,
                                              const int* __restrict__ pb, const int* __restrict__ mlist,
                                              const int* __restrict__ nend, const int* __restrict__ ncnt,
                                              ushort_t* __restrict__ naggb, ushort_t* __restrict__ pmusum,
                                              int N) {
    int idx = blockIdx.x * 256 + threadIdx.x;
    int n = idx >> 4, j = idx & 15;
    if (n >= N) return;
    int kn = nend[n], c = ncnt[n], s0 = kn - c;
    float sa[8] = {0.f, 0.f, 0.f, 0.f, 0.f, 0.f, 0.f, 0.f};
    float sp[8] = {0.f, 0.f, 0.f, 0.f, 0.f, 0.f, 0.f, 0.f};
    for (int k = 0; k < c; k++) {
        int m = mlist[s0 + k];
        int pbv = pb[s0 + k];
        ushort8 ab = *(const ushort8*)(aggb + (size_t)m * D + j * 8);
        ushort8 pv = *(const ushort8*)(pmu + (size_t)pbv * D + j * 8);
#pragma unroll
        for (int q = 0; q < 8; q++) { sa[q] += b2f(ab[q]); sp[q] += b2f(pv[q]); }
    }
    float inv = 1.0f / fmaxf((float)c, 1.0f);
    ushort8 o, q8;
#pragma unroll
    for (int q = 0; q < 8; q++) { o[q] = f2b(sa[q] * inv); q8[q] = f2b(sp[q] * inv); }
    *(ushort8*)(naggb + (size_t)n * D + j * 8) = o;
    *(ushort8*)(pmusum + (size_t)n * D + j * 8) = q8;
}

// hnb[N,128] = bf16( naggb(bf16) @ W[l] + b[l] + pmusum ), MFMA 16x16x32, 64 rows/block
__global__ __launch_bounds__(256) void k_nup(const ushort_t* __restrict__ naggb,
                                             const ushort_t* __restrict__ Wtb,
                                             const float* __restrict__ bg,
                                             const ushort_t* __restrict__ pmusum,
                                             ushort_t* __restrict__ hnb, int N, int layer) {
    __shared__ ushort_t Wl[128 * 136];  // [col][k] padded
    const ushort_t* W = Wtb + (size_t)layer * D * D;
    int t = threadIdx.x;
#pragma unroll
    for (int i = 0; i < 8; i++) {
        int cid = t + i * 256;
        int col = cid >> 4, kc = (cid & 15) * 8;
        *(short8*)&Wl[col * 136 + kc] = *(const short8*)(W + col * 128 + kc);
    }
    __syncthreads();
    int w = t >> 6, lane = t & 63;
    int r16 = lane & 15, kg = lane >> 4;
    int rowbase = blockIdx.x * 64 + w * 16;
    size_t arow = (size_t)min(rowbase + r16, N - 1) * D;
    short8 a0 = *(const short8*)(naggb + arow + 0 + kg * 8);
    short8 a1 = *(const short8*)(naggb + arow + 32 + kg * 8);
    short8 a2 = *(const short8*)(naggb + arow + 64 + kg * 8);
    short8 a3 = *(const short8*)(naggb + arow + 96 + kg * 8);
#pragma unroll
    for (int c = 0; c < 8; c++) {
        const ushort_t* wp = &Wl[(c * 16 + r16) * 136 + kg * 8];
        short8 b0 = *(const short8*)(wp + 0);
        short8 b1 = *(const short8*)(wp + 32);
        short8 b2 = *(const short8*)(wp + 64);
        short8 b3 = *(const short8*)(wp + 96);
        f32x4 acc = (f32x4){0.f, 0.f, 0.f, 0.f};
        acc = __builtin_amdgcn_mfma_f32_16x16x32_bf16(a0, b0, acc, 0, 0, 0);
        acc = __builtin_amdgcn_mfma_f32_16x16x32_bf16(a1, b1, acc, 0, 0, 0);
        acc = __builtin_amdgcn_mfma_f32_16x16x32_bf16(a2, b2, acc, 0, 0, 0);
        acc = __builtin_amdgcn_mfma_f32_16x16x32_bf16(a3, b3, acc, 0, 0, 0);
        int gcol = c * 16 + r16;
        float bias = bg[layer * D + gcol];
#pragma unroll
        for (int q = 0; q < 4; q++) {
            int grow = rowbase + kg * 4 + q;
            if (grow < N)
                hnb[(size_t)grow * D + gcol] =
                    f2b(acc[q] + bias + b2f(pmusum[(size_t)grow * D + gcol]));
        }
    }
}

extern "C" void kernel_launch(void* const* d_in, const int* in_sizes, int n_in,
                              void* d_out, int out_size, void* d_ws, size_t ws_size,
                              hipStream_t stream) {
    const float* x    = (const float*)d_in[0];
    const float* ea   = (const float*)d_in[1];
    const int* nm     = (const int*)d_in[2];
    const int* em     = (const int*)d_in[3];
    const int* cs     = (const int*)d_in[4];
    const int* batch  = (const int*)d_in[5];
    const float* Wg   = (const float*)d_in[7];
    const float* bg   = (const float*)d_in[8];
    const float* eps  = (const float*)d_in[9];
    const float* Wu   = (const float*)d_in[10];
    const float* bu   = (const float*)d_in[11];
    float* out = (float*)d_out;

    int N  = in_sizes[0] / D;
    int E  = in_sizes[1] / D;
    int M  = in_sizes[2];
    int EC = in_sizes[3];
    int P  = out_size / D;
    const int* src = cs;
    const int* dst = cs + EC;

    // workspace carve (256B aligned)
    char* base = (char*)d_ws;
    size_t off = 0;
    auto carve = [&](size_t bytes) { void* p = base + off; off += (bytes + 255) & ~(size_t)255; return p; };
    ushort_t* aggb   = (ushort_t*)carve((size_t)M * D * 2);
    uint_t*   eab4   = (uint_t*)carve((size_t)E * D);     // fp8 e4m3: 128 B/row, E-indexed
    ushort_t* xb     = (ushort_t*)carve((size_t)N * D * 2);
    ushort_t* Wtb    = (ushort_t*)carve((size_t)4 * D * D * 2);
    ushort_t* hnb    = (ushort_t*)carve((size_t)N * D * 2);
    ushort_t* naggb  = (ushort_t*)carve((size_t)N * D * 2);
    ushort_t* pmusum = (ushort_t*)carve((size_t)N * D * 2);
    ushort_t* pmu    = (ushort_t*)carve((size_t)P * D * 2);
    int* cntblk = (int*)carve((size_t)(M + N + P) * 4);
    int* ecnt = cntblk, *ncnt = cntblk + M, *pcnt = cntblk + M + N;
    int* ecur   = (int*)carve((size_t)M * 4);
    int* ncur   = (int*)carve((size_t)N * 4);
    int2* se    = (int2*)carve((size_t)EC * 8);
    int* mlist  = (int*)carve((size_t)M * 4);
    int* pb     = (int*)carve((size_t)M * 4);
    int* pstart = (int*)carve((size_t)P * 4);
    int* bsum   = (int*)carve(768 * 4);
    if (ws_size < off) return;

    // ---- build (reused across layers) ----
    hipMemsetAsync(cntblk, 0, (size_t)(M + N + P) * sizeof(int), stream);
    int mxEM = EC > M ? EC : M;
    k_histm<<<(mxEM + 255) / 256, 256, 0, stream>>>(dst, nm, batch, ecnt, ncnt, pcnt, EC, M);

    int nbe = (M + 1023) / 1024, nbn = (N + 1023) / 1024, nbp = (P + 1023) / 1024;
    k_scan1m<<<nbe + nbn + nbp, 256, 0, stream>>>(ecnt, ecur, nbe, M,
                                                  ncnt, ncur, nbn, N,
                                                  pcnt, pstart, nbp, P, bsum);
    k_scan2m<<<3, 256, 0, stream>>>(bsum, nbe, nbn, nbp);
    k_scan3m<<<(M + N + P + 255) / 256, 256, 0, stream>>>(ecur, ncur, pstart, bsum, M, N, P);

    k_scatterm<<<(mxEM + 255) / 256, 256, 0, stream>>>(dst, src, em, nm, batch,
                                                       ecur, se, ncur, mlist, pb, EC, M);
    int EA4 = E * D / 4, NX8 = N * D / 8, NW = 4 * D * D;
    k_convm<<<(EA4 + NX8 + NW + 255) / 256, 256, 0, stream>>>(ea, eab4, EA4, x, xb, NX8, Wg, Wtb, NW);

    // ---- compute ----
    int mb = (M * 16 + 255) / 256;
    int nb = (N * 16 + 255) / 256;
    for (int i = 0; i < 4; i++) {
        const ushort_t* hnp = (i == 0) ? xb : hnb;
        if (i > 0) {
            k_nagg<<<nb, 256, 0, stream>>>(aggb, pmu, pb, mlist,
                                           ncur, ncnt, naggb, pmusum, N);
            k_nup<<<(N + 63) / 64, 256, 0, stream>>>(naggb, Wtb, bg, pmusum, hnb, N, i - 1);
        }
        k_edge<<<mb, 256, 0, stream>>>(hnp, eab4, nm, se, ecur, ecnt, aggb, eps, i, M);
        k_patch_tf<<<P, 256, 0, stream>>>(aggb, pstart, pcnt, Wg, bg, Wu, bu, pmu, out, i);
    }
}

// Round 14
// 593.287 us; speedup vs baseline: 1.0417x; 1.0104x over previous
//
#include <hip/hip_runtime.h>
#include <hip/hip_bf16.h>

#define D 128
#define DV 32   // float4 per row

typedef float4 f4;
typedef unsigned short ushort_t;
typedef unsigned int uint_t;
typedef __attribute__((ext_vector_type(8))) short short8;
typedef __attribute__((ext_vector_type(8))) unsigned short ushort8;
typedef __attribute__((ext_vector_type(4))) float f32x4;
typedef __attribute__((ext_vector_type(2))) float f32x2;

__device__ __forceinline__ void f4add(f4& a, const f4& b) {
    a.x += b.x; a.y += b.y; a.z += b.z; a.w += b.w;
}
__device__ __forceinline__ float b2f(ushort_t u) {
    union { unsigned int i; float f; } v; v.i = ((unsigned int)u) << 16; return v.f;
}
__device__ __forceinline__ ushort_t f2b(float f) {
    __hip_bfloat16 b = __float2bfloat16(f);
    return *reinterpret_cast<ushort_t*>(&b);
}
// fp8 e4m3 (OCP on gfx950) hw converts
__device__ __forceinline__ f4 fp8x4_to_f4(uint_t v) {
    f32x2 lo = __builtin_amdgcn_cvt_pk_f32_fp8((int)v, false);
    f32x2 hi = __builtin_amdgcn_cvt_pk_f32_fp8((int)v, true);
    return make_float4(lo[0], lo[1], hi[0], hi[1]);
}
__device__ __forceinline__ uint_t f4_to_fp8x4(f4 v) {
    int r = 0;
    r = __builtin_amdgcn_cvt_pk_fp8_f32(v.x, v.y, r, false);
    r = __builtin_amdgcn_cvt_pk_fp8_f32(v.z, v.w, r, true);
    return (uint_t)r;
}

// ================= build phase =================
__global__ void k_histm(const int* __restrict__ dst, const int* __restrict__ nm,
                        const int* __restrict__ batch, int* __restrict__ ecnt,
                        int* __restrict__ ncnt, int* __restrict__ pcnt, int EC, int M) {
    int c = blockIdx.x * 256 + threadIdx.x;
    if (c < EC) atomicAdd(&ecnt[dst[c]], 1);
    if (c < M) { atomicAdd(&ncnt[nm[c]], 1); atomicAdd(&pcnt[batch[c]], 1); }
}

// merged scan stage 1: three arrays, block-local exclusive scan (span 1024)
__global__ __launch_bounds__(256) void k_scan1m(const int* __restrict__ inE, int* __restrict__ outE, int nbe, int nE,
                                                const int* __restrict__ inN, int* __restrict__ outN, int nbn, int nN,
                                                const int* __restrict__ inP, int* __restrict__ outP, int nbp, int nP,
                                                int* __restrict__ bsum) {
    __shared__ int ts[256];
    int b = blockIdx.x, t = threadIdx.x;
    const int* in; int* out; int* bs; int lb, n;
    if (b < nbe)            { in = inE; out = outE; bs = bsum;       lb = b;             n = nE; }
    else if (b < nbe + nbn) { in = inN; out = outN; bs = bsum + 256; lb = b - nbe;       n = nN; }
    else                    { in = inP; out = outP; bs = bsum + 512; lb = b - nbe - nbn; n = nP; }
    int base = lb * 1024 + t * 4;
    int v0 = base + 0 < n ? in[base + 0] : 0;
    int v1 = base + 1 < n ? in[base + 1] : 0;
    int v2 = base + 2 < n ? in[base + 2] : 0;
    int v3 = base + 3 < n ? in[base + 3] : 0;
    int tot = v0 + v1 + v2 + v3;
    ts[t] = tot; __syncthreads();
    for (int off = 1; off < 256; off <<= 1) {
        int x = (t >= off) ? ts[t - off] : 0; __syncthreads();
        ts[t] += x; __syncthreads();
    }
    int ex = ts[t] - tot;
    if (base + 0 < n) out[base + 0] = ex;
    if (base + 1 < n) out[base + 1] = ex + v0;
    if (base + 2 < n) out[base + 2] = ex + v0 + v1;
    if (base + 3 < n) out[base + 3] = ex + v0 + v1 + v2;
    if (t == 255) bs[lb] = ts[255];
}

// stage 2: 3 blocks, parallel in-place exclusive scan of <=1024 block sums
__global__ __launch_bounds__(256) void k_scan2m(int* __restrict__ bsum, int nbe, int nbn, int nbp) {
    __shared__ int ts[256];
    int b = blockIdx.x, t = threadIdx.x;
    int* a; int n;
    if (b == 0)      { a = bsum;       n = nbe; }
    else if (b == 1) { a = bsum + 256; n = nbn; }
    else             { a = bsum + 512; n = nbp; }
    int base = t * 4;
    int v0 = base + 0 < n ? a[base + 0] : 0;
    int v1 = base + 1 < n ? a[base + 1] : 0;
    int v2 = base + 2 < n ? a[base + 2] : 0;
    int v3 = base + 3 < n ? a[base + 3] : 0;
    int tot = v0 + v1 + v2 + v3;
    ts[t] = tot; __syncthreads();
    for (int off = 1; off < 256; off <<= 1) {
        int x = (t >= off) ? ts[t - off] : 0; __syncthreads();
        ts[t] += x; __syncthreads();
    }
    int ex = ts[t] - tot;
    if (base + 0 < n) a[base + 0] = ex;
    if (base + 1 < n) a[base + 1] = ex + v0;
    if (base + 2 < n) a[base + 2] = ex + v0 + v1;
    if (base + 3 < n) a[base + 3] = ex + v0 + v1 + v2;
}

__global__ void k_scan3m(int* __restrict__ outE, int* __restrict__ outN, int* __restrict__ outP,
                         const int* __restrict__ bsum, int nE, int nN, int nP) {
    int i = blockIdx.x * 256 + threadIdx.x;
    if (i < nE) { outE[i] += bsum[i >> 10]; return; }
    i -= nE;
    if (i < nN) { outN[i] += bsum[256 + (i >> 10)]; return; }
    i -= nN;
    if (i < nP) { outP[i] += bsum[512 + (i >> 10)]; }
}

// merged scatter: edge CSR payloads (packed int2) + node copy lists (packed int2: m, batch[m])
__global__ void k_scatterm(const int* __restrict__ dst, const int* __restrict__ src,
                           const int* __restrict__ em, const int* __restrict__ nm,
                           const int* __restrict__ batch,
                           int* __restrict__ ecur, int2* __restrict__ se,
                           int* __restrict__ ncur, int2* __restrict__ mp,
                           int EC, int M) {
    int c = blockIdx.x * 256 + threadIdx.x;
    if (c < EC) {
        int p = atomicAdd(&ecur[dst[c]], 1);
        se[p] = make_int2(nm[src[c]], em[c]);
    }
    if (c < M) {
        int p = atomicAdd(&ncur[nm[c]], 1);
        mp[p] = make_int2(c, batch[c]);
    }
}

// merged converts: ea->fp8 (contiguous), x->bf16, W->bf16 transposed
__global__ void k_convm(const float* __restrict__ ea, uint_t* __restrict__ eab4, int EA4,
                        const float* __restrict__ x, ushort_t* __restrict__ xb, int NX8,
                        const float* __restrict__ Wg, ushort_t* __restrict__ Wtb, int NW) {
    int i = blockIdx.x * 256 + threadIdx.x;
    if (i < EA4) {  // 4 f32 -> packed fp8x4 per thread, contiguous stream
        f4 v = *((const f4*)ea + (size_t)i);
        eab4[i] = f4_to_fp8x4(v);
        return;
    }
    i -= EA4;
    if (i < NX8) {
        const f4* p = (const f4*)x + (size_t)i * 2;
        f4 v0 = p[0], v1 = p[1];
        ushort4 o0, o1;
        o0.x = f2b(v0.x); o0.y = f2b(v0.y); o0.z = f2b(v0.z); o0.w = f2b(v0.w);
        o1.x = f2b(v1.x); o1.y = f2b(v1.y); o1.z = f2b(v1.z); o1.w = f2b(v1.w);
        *(ushort4*)(xb + (size_t)i * 8) = o0;
        *(ushort4*)(xb + (size_t)i * 8 + 4) = o1;
        return;
    }
    i -= NX8;
    if (i < NW) {
        int l = i >> 14, rem = i & 16383;
        int col = rem >> 7, k = rem & 127;
        Wtb[(size_t)l * 16384 + col * 128 + k] = f2b(Wg[(size_t)l * 16384 + k * 128 + col]);
    }
}

// ================= compute phase =================
// aggb[d] = bf16( (1+eps)*h[nm[d]] + sum relu(h[se.x] + fp8dec(eab4[se.y])) )
// 16 lanes/row, 16B loads; packed int2 edge indices.
__global__ __launch_bounds__(256) void k_edge(const ushort_t* __restrict__ hnb,
                                              const uint_t* __restrict__ eab4,
                                              const int* __restrict__ nm, const int2* __restrict__ se,
                                              const int* __restrict__ eend, const int* __restrict__ ecnt,
                                              ushort_t* __restrict__ aggb,
                                              const float* __restrict__ eps, int layer, int M) {
    int idx = blockIdx.x * 256 + threadIdx.x;
    int d = idx >> 4, j = idx & 15;   // j: 8-col chunk
    if (d >= M) return;
    float s = 1.0f + eps[layer];
    ushort8 hb = *(const ushort8*)(hnb + (size_t)nm[d] * D + j * 8);
    float acc[8];
#pragma unroll
    for (int q = 0; q < 8; q++) acc[q] = b2f(hb[q]) * s;
    int kn = eend[d], k0 = kn - ecnt[d];
    int k = k0;
    for (; k + 2 <= kn; k += 2) {
        int2 se0 = se[k], se1 = se[k + 1];
        uint2 p0 = *(const uint2*)(eab4 + (size_t)se0.y * 32 + j * 2);
        uint2 p1 = *(const uint2*)(eab4 + (size_t)se1.y * 32 + j * 2);
        ushort8 h0 = *(const ushort8*)(hnb + (size_t)se0.x * D + j * 8);
        ushort8 h1 = *(const ushort8*)(hnb + (size_t)se1.x * D + j * 8);
        f4 e0a = fp8x4_to_f4(p0.x), e0b = fp8x4_to_f4(p0.y);
        f4 e1a = fp8x4_to_f4(p1.x), e1b = fp8x4_to_f4(p1.y);
        acc[0] += fmaxf(b2f(h0[0]) + e0a.x, 0.f) + fmaxf(b2f(h1[0]) + e1a.x, 0.f);
        acc[1] += fmaxf(b2f(h0[1]) + e0a.y, 0.f) + fmaxf(b2f(h1[1]) + e1a.y, 0.f);
        acc[2] += fmaxf(b2f(h0[2]) + e0a.z, 0.f) + fmaxf(b2f(h1[2]) + e1a.z, 0.f);
        acc[3] += fmaxf(b2f(h0[3]) + e0a.w, 0.f) + fmaxf(b2f(h1[3]) + e1a.w, 0.f);
        acc[4] += fmaxf(b2f(h0[4]) + e0b.x, 0.f) + fmaxf(b2f(h1[4]) + e1b.x, 0.f);
        acc[5] += fmaxf(b2f(h0[5]) + e0b.y, 0.f) + fmaxf(b2f(h1[5]) + e1b.y, 0.f);
        acc[6] += fmaxf(b2f(h0[6]) + e0b.z, 0.f) + fmaxf(b2f(h1[6]) + e1b.z, 0.f);
        acc[7] += fmaxf(b2f(h0[7]) + e0b.w, 0.f) + fmaxf(b2f(h1[7]) + e1b.w, 0.f);
    }
    if (k < kn) {
        int2 se0 = se[k];
        uint2 p0 = *(const uint2*)(eab4 + (size_t)se0.y * 32 + j * 2);
        ushort8 h0 = *(const ushort8*)(hnb + (size_t)se0.x * D + j * 8);
        f4 e0a = fp8x4_to_f4(p0.x), e0b = fp8x4_to_f4(p0.y);
        acc[0] += fmaxf(b2f(h0[0]) + e0a.x, 0.f);
        acc[1] += fmaxf(b2f(h0[1]) + e0a.y, 0.f);
        acc[2] += fmaxf(b2f(h0[2]) + e0a.z, 0.f);
        acc[3] += fmaxf(b2f(h0[3]) + e0a.w, 0.f);
        acc[4] += fmaxf(b2f(h0[4]) + e0b.x, 0.f);
        acc[5] += fmaxf(b2f(h0[5]) + e0b.y, 0.f);
        acc[6] += fmaxf(b2f(h0[6]) + e0b.z, 0.f);
        acc[7] += fmaxf(b2f(h0[7]) + e0b.w, 0.f);
    }
    ushort8 o;
#pragma unroll
    for (int q = 0; q < 8; q++) o[q] = f2b(acc[q]);
    *(ushort8*)(aggb + (size_t)d * D + j * 8) = o;
}

// fused per-patch: mean over contiguous aggb rows (16B loads, 16 lanes x 16 row-groups),
// then split-K GEMV (all 256 threads):
//   layer<3 : pmu[p] = bf16(relu((mean @ Wg[l] + bg[l]) @ Wu[l] + bu[l]))
//   layer==3: out[p] = mean @ Wg[3] + bg[3]   (f32)
__global__ __launch_bounds__(256) void k_patch_tf(const ushort_t* __restrict__ aggb,
                                                  const int* __restrict__ pstart, const int* __restrict__ pcnt,
                                                  const float* __restrict__ Wg, const float* __restrict__ bg,
                                                  const float* __restrict__ Wu, const float* __restrict__ bu,
                                                  ushort_t* __restrict__ pmu, float* __restrict__ outv, int layer) {
    __shared__ float red[256 * 8];   // 8KB
    __shared__ float row[D];
    __shared__ float gp[256];
    int p = blockIdx.x;
    int t = threadIdx.x, j = t & 15, r = t >> 4;   // 16 row-groups of 16 lanes
    int s0 = pstart[p], c = pcnt[p];
    float acc[8] = {0.f, 0.f, 0.f, 0.f, 0.f, 0.f, 0.f, 0.f};
    for (int k = r; k < c; k += 16) {
        ushort8 ab = *(const ushort8*)(aggb + (size_t)(s0 + k) * D + j * 8);
#pragma unroll
        for (int q = 0; q < 8; q++) acc[q] += b2f(ab[q]);
    }
#pragma unroll
    for (int q = 0; q < 8; q++) red[t * 8 + q] = acc[q];
    __syncthreads();
    for (int step = 8; step >= 1; step >>= 1) {
        if (r < step) {
#pragma unroll
            for (int q = 0; q < 8; q++) red[t * 8 + q] += red[(t + 16 * step) * 8 + q];
        }
        __syncthreads();
    }
    if (r == 0) {
        float inv = 1.0f / fmaxf((float)c, 1.0f);
#pragma unroll
        for (int q = 0; q < 8; q++) row[j * 8 + q] = red[t * 8 + q] * inv;
    }
    __syncthreads();
    // phase 1 GEMV, K split across two thread-halves
    int col = t & 127, half = t >> 7;
    {
        const float* W = Wg + (size_t)layer * D * D;
        float g = 0.f;
        int kb = half * 64;
#pragma unroll 8
        for (int k = 0; k < 64; k++) g += row[kb + k] * W[(kb + k) * D + col];
        gp[t] = g;
    }
    __syncthreads();
    if (layer == 3) {
        if (t < D) outv[(size_t)p * D + t] = gp[t] + gp[t + 128] + bg[layer * D + t];
        return;
    }
    __shared__ float mid[D];
    if (t < D) mid[t] = gp[t] + gp[t + 128] + bg[layer * D + t];
    __syncthreads();
    {
        const float* W2 = Wu + (size_t)layer * D * D;
        float g = 0.f;
        int kb = half * 64;
#pragma unroll 8
        for (int k = 0; k < 64; k++) g += mid[kb + k] * W2[(kb + k) * D + col];
        gp[t] = g;
    }
    __syncthreads();
    if (t < D) pmu[(size_t)p * D + t] = f2b(fmaxf(gp[t] + gp[t + 128] + bu[layer * D + t], 0.f));
}

// per node: naggb[n] = bf16(mean over copies of aggb); pmusum[n] = bf16(mean of pmu[mp.y])
// 16 lanes/node, 16B loads; packed int2 (m, batch) stream; x2 unrolled gathers.
__global__ __launch_bounds__(256) void k_nagg(const ushort_t* __restrict__ aggb,
                                              const ushort_t* __restrict__ pmu,
                                              const int2* __restrict__ mp,
                                              const int* __restrict__ nend, const int* __restrict__ ncnt,
                                              ushort_t* __restrict__ naggb, ushort_t* __restrict__ pmusum,
                                              int N) {
    int idx = blockIdx.x * 256 + threadIdx.x;
    int n = idx >> 4, j = idx & 15;
    if (n >= N) return;
    int kn = nend[n], c = ncnt[n], s0 = kn - c;
    float sa[8] = {0.f, 0.f, 0.f, 0.f, 0.f, 0.f, 0.f, 0.f};
    float sp[8] = {0.f, 0.f, 0.f, 0.f, 0.f, 0.f, 0.f, 0.f};
    int k = 0;
    for (; k + 2 <= c; k += 2) {
        int2 a0 = mp[s0 + k], a1 = mp[s0 + k + 1];
        ushort8 ab0 = *(const ushort8*)(aggb + (size_t)a0.x * D + j * 8);
        ushort8 ab1 = *(const ushort8*)(aggb + (size_t)a1.x * D + j * 8);
        ushort8 pv0 = *(const ushort8*)(pmu + (size_t)a0.y * D + j * 8);
        ushort8 pv1 = *(const ushort8*)(pmu + (size_t)a1.y * D + j * 8);
#pragma unroll
        for (int q = 0; q < 8; q++) {
            sa[q] += b2f(ab0[q]) + b2f(ab1[q]);
            sp[q] += b2f(pv0[q]) + b2f(pv1[q]);
        }
    }
    if (k < c) {
        int2 a0 = mp[s0 + k];
        ushort8 ab0 = *(const ushort8*)(aggb + (size_t)a0.x * D + j * 8);
        ushort8 pv0 = *(const ushort8*)(pmu + (size_t)a0.y * D + j * 8);
#pragma unroll
        for (int q = 0; q < 8; q++) { sa[q] += b2f(ab0[q]); sp[q] += b2f(pv0[q]); }
    }
    float inv = 1.0f / fmaxf((float)c, 1.0f);
    ushort8 o, q8;
#pragma unroll
    for (int q = 0; q < 8; q++) { o[q] = f2b(sa[q] * inv); q8[q] = f2b(sp[q] * inv); }
    *(ushort8*)(naggb + (size_t)n * D + j * 8) = o;
    *(ushort8*)(pmusum + (size_t)n * D + j * 8) = q8;
}

// hnb[N,128] = bf16( naggb(bf16) @ W[l] + b[l] + pmusum ), MFMA 16x16x32, 64 rows/block
__global__ __launch_bounds__(256) void k_nup(const ushort_t* __restrict__ naggb,
                                             const ushort_t* __restrict__ Wtb,
                                             const float* __restrict__ bg,
                                             const ushort_t* __restrict__ pmusum,
                                             ushort_t* __restrict__ hnb, int N, int layer) {
    __shared__ ushort_t Wl[128 * 136];  // [col][k] padded
    const ushort_t* W = Wtb + (size_t)layer * D * D;
    int t = threadIdx.x;
#pragma unroll
    for (int i = 0; i < 8; i++) {
        int cid = t + i * 256;
        int col = cid >> 4, kc = (cid & 15) * 8;
        *(short8*)&Wl[col * 136 + kc] = *(const short8*)(W + col * 128 + kc);
    }
    __syncthreads();
    int w = t >> 6, lane = t & 63;
    int r16 = lane & 15, kg = lane >> 4;
    int rowbase = blockIdx.x * 64 + w * 16;
    size_t arow = (size_t)min(rowbase + r16, N - 1) * D;
    short8 a0 = *(const short8*)(naggb + arow + 0 + kg * 8);
    short8 a1 = *(const short8*)(naggb + arow + 32 + kg * 8);
    short8 a2 = *(const short8*)(naggb + arow + 64 + kg * 8);
    short8 a3 = *(const short8*)(naggb + arow + 96 + kg * 8);
#pragma unroll
    for (int c = 0; c < 8; c++) {
        const ushort_t* wp = &Wl[(c * 16 + r16) * 136 + kg * 8];
        short8 b0 = *(const short8*)(wp + 0);
        short8 b1 = *(const short8*)(wp + 32);
        short8 b2 = *(const short8*)(wp + 64);
        short8 b3 = *(const short8*)(wp + 96);
        f32x4 acc = (f32x4){0.f, 0.f, 0.f, 0.f};
        acc = __builtin_amdgcn_mfma_f32_16x16x32_bf16(a0, b0, acc, 0, 0, 0);
        acc = __builtin_amdgcn_mfma_f32_16x16x32_bf16(a1, b1, acc, 0, 0, 0);
        acc = __builtin_amdgcn_mfma_f32_16x16x32_bf16(a2, b2, acc, 0, 0, 0);
        acc = __builtin_amdgcn_mfma_f32_16x16x32_bf16(a3, b3, acc, 0, 0, 0);
        int gcol = c * 16 + r16;
        float bias = bg[layer * D + gcol];
#pragma unroll
        for (int q = 0; q < 4; q++) {
            int grow = rowbase + kg * 4 + q;
            if (grow < N)
                hnb[(size_t)grow * D + gcol] =
                    f2b(acc[q] + bias + b2f(pmusum[(size_t)grow * D + gcol]));
        }
    }
}

extern "C" void kernel_launch(void* const* d_in, const int* in_sizes, int n_in,
                              void* d_out, int out_size, void* d_ws, size_t ws_size,
                              hipStream_t stream) {
    const float* x    = (const float*)d_in[0];
    const float* ea   = (const float*)d_in[1];
    const int* nm     = (const int*)d_in[2];
    const int* em     = (const int*)d_in[3];
    const int* cs     = (const int*)d_in[4];
    const int* batch  = (const int*)d_in[5];
    const float* Wg   = (const float*)d_in[7];
    const float* bg   = (const float*)d_in[8];
    const float* eps  = (const float*)d_in[9];
    const float* Wu   = (const float*)d_in[10];
    const float* bu   = (const float*)d_in[11];
    float* out = (float*)d_out;

    int N  = in_sizes[0] / D;
    int E  = in_sizes[1] / D;
    int M  = in_sizes[2];
    int EC = in_sizes[3];
    int P  = out_size / D;
    const int* src = cs;
    const int* dst = cs + EC;

    // workspace carve (256B aligned)
    char* base = (char*)d_ws;
    size_t off = 0;
    auto carve = [&](size_t bytes) { void* p = base + off; off += (bytes + 255) & ~(size_t)255; return p; };
    ushort_t* aggb   = (ushort_t*)carve((size_t)M * D * 2);
    uint_t*   eab4   = (uint_t*)carve((size_t)E * D);     // fp8 e4m3: 128 B/row, E-indexed
    ushort_t* xb     = (ushort_t*)carve((size_t)N * D * 2);
    ushort_t* Wtb    = (ushort_t*)carve((size_t)4 * D * D * 2);
    ushort_t* hnb    = (ushort_t*)carve((size_t)N * D * 2);
    ushort_t* naggb  = (ushort_t*)carve((size_t)N * D * 2);
    ushort_t* pmusum = (ushort_t*)carve((size_t)N * D * 2);
    ushort_t* pmu    = (ushort_t*)carve((size_t)P * D * 2);
    int* cntblk = (int*)carve((size_t)(M + N + P) * 4);
    int* ecnt = cntblk, *ncnt = cntblk + M, *pcnt = cntblk + M + N;
    int* ecur   = (int*)carve((size_t)M * 4);
    int* ncur   = (int*)carve((size_t)N * 4);
    int2* se    = (int2*)carve((size_t)EC * 8);
    int2* mp    = (int2*)carve((size_t)M * 8);
    int* pstart = (int*)carve((size_t)P * 4);
    int* bsum   = (int*)carve(768 * 4);
    if (ws_size < off) return;

    // ---- build (reused across layers) ----
    hipMemsetAsync(cntblk, 0, (size_t)(M + N + P) * sizeof(int), stream);
    int mxEM = EC > M ? EC : M;
    k_histm<<<(mxEM + 255) / 256, 256, 0, stream>>>(dst, nm, batch, ecnt, ncnt, pcnt, EC, M);

    int nbe = (M + 1023) / 1024, nbn = (N + 1023) / 1024, nbp = (P + 1023) / 1024;
    k_scan1m<<<nbe + nbn + nbp, 256, 0, stream>>>(ecnt, ecur, nbe, M,
                                                  ncnt, ncur, nbn, N,
                                                  pcnt, pstart, nbp, P, bsum);
    k_scan2m<<<3, 256, 0, stream>>>(bsum, nbe, nbn, nbp);
    k_scan3m<<<(M + N + P + 255) / 256, 256, 0, stream>>>(ecur, ncur, pstart, bsum, M, N, P);

    k_scatterm<<<(mxEM + 255) / 256, 256, 0, stream>>>(dst, src, em, nm, batch,
                                                       ecur, se, ncur, mp, EC, M);
    int EA4 = E * D / 4, NX8 = N * D / 8, NW = 4 * D * D;
    k_convm<<<(EA4 + NX8 + NW + 255) / 256, 256, 0, stream>>>(ea, eab4, EA4, x, xb, NX8, Wg, Wtb, NW);

    // ---- compute ----
    int mb = (M * 16 + 255) / 256;
    int nb = (N * 16 + 255) / 256;
    for (int i = 0; i < 4; i++) {
        const ushort_t* hnp = (i == 0) ? xb : hnb;
        if (i > 0) {
            k_nagg<<<nb, 256, 0, stream>>>(aggb, pmu, mp, ncur, ncnt, naggb, pmusum, N);
            k_nup<<<(N + 63) / 64, 256, 0, stream>>>(naggb, Wtb, bg, pmusum, hnb, N, i - 1);
        }
        k_edge<<<mb, 256, 0, stream>>>(hnp, eab4, nm, se, ecur, ecnt, aggb, eps, i, M);
        k_patch_tf<<<P, 256, 0, stream>>>(aggb, pstart, pcnt, Wg, bg, Wu, bu, pmu, out, i);
    }
}